// Round 1
// baseline (1760.578 us; speedup 1.0000x reference)
//
#include <hip/hip_runtime.h>

// EllipticGNN: 2-layer GCN + linear head, f32.
// Inputs: x[N,165], edge_index[2,E] int32, W1[165,128], b1[128],
//         W2[128,128], b2[128], W3[128,2], b3[2]. Output: [N,2] f32.

constexpr int NN   = 100000;
constexpr int NE   = 1600000;
constexpr int FIN  = 165;
constexpr int HID  = 128;

__global__ __launch_bounds__(256) void k_init_deg(float* __restrict__ deg) {
    int i = blockIdx.x * 256 + threadIdx.x;
    if (i < NN) deg[i] = 1.0f;   // self-loop
}

__global__ __launch_bounds__(256) void k_deg(const int* __restrict__ dst,
                                             float* __restrict__ deg) {
    int i = blockIdx.x * 256 + threadIdx.x;
    if (i < NE) atomicAdd(&deg[dst[i]], 1.0f);
}

__global__ __launch_bounds__(256) void k_dinv(float* __restrict__ deg) {
    int i = blockIdx.x * 256 + threadIdx.x;
    if (i < NN) deg[i] = rsqrtf(deg[i]);   // deg >= 1 always
}

// Y[base+r][t] = sum_k X[base+r][k] * W[k][t]; 128 threads = 128 cols,
// R rows per block. X loads are wave-uniform -> scalar loads.
template<int K, int R>
__global__ __launch_bounds__(128) void k_gemm(const float* __restrict__ X,
                                              const float* __restrict__ W,
                                              float* __restrict__ Y) {
    const int t = threadIdx.x;
    const long base = (long)blockIdx.x * R;
    float acc[R];
#pragma unroll
    for (int r = 0; r < R; ++r) acc[r] = 0.0f;
    for (int k = 0; k < K; ++k) {
        float wv = W[k * HID + t];
#pragma unroll
        for (int r = 0; r < R; ++r)
            acc[r] += X[(base + r) * K + k] * wv;
    }
#pragma unroll
    for (int r = 0; r < R; ++r)
        Y[(base + r) * HID + t] = acc[r];
}

// out[i][:] = Hm[i][:] * dinv[i]^2 + b[:]   (self-loop term + bias)
__global__ __launch_bounds__(256) void k_selfinit(const float* __restrict__ Hm,
                                                  const float* __restrict__ dinv,
                                                  const float* __restrict__ b,
                                                  float* __restrict__ out) {
    long tid = (long)blockIdx.x * 256 + threadIdx.x;
    if (tid >= (long)NN * HID) return;
    int i = (int)(tid >> 7), j = (int)(tid & 127);
    float di = dinv[i];
    out[tid] = Hm[tid] * di * di + b[j];
}

// per-edge scatter: out[dst] += Hm[src] * dinv[src]*dinv[dst]
// 128 threads per edge (one float each); edge index is wave-uniform.
__global__ __launch_bounds__(256) void k_scatter(const float* __restrict__ Hm,
                                                 const int* __restrict__ srcA,
                                                 const int* __restrict__ dstA,
                                                 const float* __restrict__ dinv,
                                                 float* __restrict__ out) {
    long tid = (long)blockIdx.x * 256 + threadIdx.x;
    int e = (int)(tid >> 7);
    int j = (int)(tid & 127);
    if (e >= NE) return;
    int s = srcA[e], d = dstA[e];
    float nrm = dinv[s] * dinv[d];
    atomicAdd(&out[(long)d * HID + j], Hm[(long)s * HID + j] * nrm);
}

__global__ __launch_bounds__(256) void k_relu4(float4* __restrict__ x, long n4) {
    long i = (long)blockIdx.x * 256 + threadIdx.x;
    if (i < n4) {
        float4 v = x[i];
        v.x = fmaxf(v.x, 0.f); v.y = fmaxf(v.y, 0.f);
        v.z = fmaxf(v.z, 0.f); v.w = fmaxf(v.w, 0.f);
        x[i] = v;
    }
}

// out[i][c] = sum_k h[i][k]*W3[k][c] + b3[c], c in {0,1}
__global__ __launch_bounds__(256) void k_head(const float* __restrict__ h,
                                              const float* __restrict__ W3,
                                              const float* __restrict__ b3,
                                              float* __restrict__ out) {
    __shared__ float w[HID * 2];
    int t = threadIdx.x;
    w[t] = W3[t];               // 256 = HID*2 exactly
    __syncthreads();
    int i = blockIdx.x * 256 + t;
    if (i >= NN) return;
    const float4* row = (const float4*)(h + (long)i * HID);
    float a0 = 0.f, a1 = 0.f;
#pragma unroll
    for (int k4 = 0; k4 < HID / 4; ++k4) {
        float4 v = row[k4];
        a0 += v.x * w[(k4 * 4 + 0) * 2 + 0] + v.y * w[(k4 * 4 + 1) * 2 + 0]
            + v.z * w[(k4 * 4 + 2) * 2 + 0] + v.w * w[(k4 * 4 + 3) * 2 + 0];
        a1 += v.x * w[(k4 * 4 + 0) * 2 + 1] + v.y * w[(k4 * 4 + 1) * 2 + 1]
            + v.z * w[(k4 * 4 + 2) * 2 + 1] + v.w * w[(k4 * 4 + 3) * 2 + 1];
    }
    out[(long)i * 2 + 0] = a0 + b3[0];
    out[(long)i * 2 + 1] = a1 + b3[1];
}

extern "C" void kernel_launch(void* const* d_in, const int* in_sizes, int n_in,
                              void* d_out, int out_size, void* d_ws, size_t ws_size,
                              hipStream_t stream) {
    const float* x   = (const float*)d_in[0];
    const int*   ei  = (const int*)d_in[1];
    const float* W1  = (const float*)d_in[2];
    const float* b1  = (const float*)d_in[3];
    const float* W2  = (const float*)d_in[4];
    const float* b2  = (const float*)d_in[5];
    const float* W3  = (const float*)d_in[6];
    const float* b3  = (const float*)d_in[7];
    float* out = (float*)d_out;

    const int* srcA = ei;           // edge_index[0]
    const int* dstA = ei + NE;      // edge_index[1]

    char* wsb = (char*)d_ws;
    float* dinv = (float*)wsb;                                   // N f32
    float* buf1 = (float*)(wsb + (1 << 20));                     // N*H f32
    float* buf2 = (float*)(wsb + (1 << 20) + (size_t)NN * HID * 4);

    const int nb_n   = (NN + 255) / 256;         // 391
    const int nb_e   = (NE + 255) / 256;         // 6250
    const int nb_nh  = NN * HID / 256;           // 50000
    const int nb_sc  = (int)((long)NE * HID / 256);  // 800000
    const int nb_r4  = (int)((long)NN * HID / 4 / 256); // 12500

    // degree -> dinv
    k_init_deg<<<nb_n, 256, 0, stream>>>(dinv);
    k_deg<<<nb_e, 256, 0, stream>>>(dstA, dinv);
    k_dinv<<<nb_n, 256, 0, stream>>>(dinv);

    // layer 1
    k_gemm<FIN, 8><<<NN / 8, 128, 0, stream>>>(x, W1, buf1);
    k_selfinit<<<nb_nh, 256, 0, stream>>>(buf1, dinv, b1, buf2);
    k_scatter<<<nb_sc, 256, 0, stream>>>(buf1, srcA, dstA, dinv, buf2);
    k_relu4<<<nb_r4, 256, 0, stream>>>((float4*)buf2, (long)NN * HID / 4);

    // layer 2
    k_gemm<HID, 8><<<NN / 8, 128, 0, stream>>>(buf2, W2, buf1);
    k_selfinit<<<nb_nh, 256, 0, stream>>>(buf1, dinv, b2, buf2);
    k_scatter<<<nb_sc, 256, 0, stream>>>(buf1, srcA, dstA, dinv, buf2);
    k_relu4<<<nb_r4, 256, 0, stream>>>((float4*)buf2, (long)NN * HID / 4);

    // head
    k_head<<<nb_n, 256, 0, stream>>>(buf2, W3, b3, out);
}

// Round 2
// 694.349 us; speedup vs baseline: 2.5356x; 2.5356x over previous
//
#include <hip/hip_runtime.h>

// EllipticGNN: 2-layer GCN + linear head, f32. CSR-gather aggregation.

constexpr int NN   = 100000;
constexpr int NE   = 1600000;
constexpr int FIN  = 165;
constexpr int HID  = 128;

__global__ __launch_bounds__(256) void k_zero_counts(int* __restrict__ c) {
    int i = blockIdx.x * 256 + threadIdx.x;
    if (i < NN) c[i] = 0;
}

__global__ __launch_bounds__(256) void k_hist(const int* __restrict__ dst,
                                              int* __restrict__ c) {
    int i = blockIdx.x * 256 + threadIdx.x;
    if (i < NE) atomicAdd(&c[dst[i]], 1);
}

__global__ __launch_bounds__(256) void k_dinv(const int* __restrict__ c,
                                              float* __restrict__ dinv) {
    int i = blockIdx.x * 256 + threadIdx.x;
    if (i < NN) dinv[i] = rsqrtf((float)c[i] + 1.0f);   // +1 self-loop
}

// block-level exclusive scan of counts -> rowptr (partial), block sums -> bsum
__global__ __launch_bounds__(256) void k_scanA(const int* __restrict__ c,
                                               int* __restrict__ rowptr,
                                               int* __restrict__ bsum) {
    __shared__ int s[256];
    int t = threadIdx.x;
    int i = blockIdx.x * 256 + t;
    int v = (i < NN) ? c[i] : 0;
    s[t] = v; __syncthreads();
    for (int off = 1; off < 256; off <<= 1) {
        int add = (t >= off) ? s[t - off] : 0;
        __syncthreads();
        s[t] += add;
        __syncthreads();
    }
    if (i < NN) rowptr[i] = s[t] - v;          // exclusive within block
    if (t == 255) bsum[blockIdx.x] = s[255];
}

// exclusive scan of block sums in place (nb <= 512)
__global__ __launch_bounds__(512) void k_scanB(int* __restrict__ bsum, int nb) {
    __shared__ int s[512];
    int t = threadIdx.x;
    int v = (t < nb) ? bsum[t] : 0;
    s[t] = v; __syncthreads();
    for (int off = 1; off < 512; off <<= 1) {
        int add = (t >= off) ? s[t - off] : 0;
        __syncthreads();
        s[t] += add;
        __syncthreads();
    }
    if (t < nb) bsum[t] = s[t] - v;
}

// add block offsets; re-zero counts (reused as fill cursor); rowptr[NN] = NE
__global__ __launch_bounds__(256) void k_scanC(int* __restrict__ rowptr,
                                               const int* __restrict__ bsum,
                                               int* __restrict__ c) {
    int i = blockIdx.x * 256 + threadIdx.x;
    if (i < NN) { rowptr[i] += bsum[blockIdx.x]; c[i] = 0; }
    if (i == 0) rowptr[NN] = NE;
}

__global__ __launch_bounds__(256) void k_fill(const int* __restrict__ src,
                                              const int* __restrict__ dst,
                                              const float* __restrict__ dinv,
                                              const int* __restrict__ rowptr,
                                              int* __restrict__ cur,
                                              int* __restrict__ col,
                                              float* __restrict__ wv) {
    int e = blockIdx.x * 256 + threadIdx.x;
    if (e >= NE) return;
    int s = src[e], d = dst[e];
    int pos = rowptr[d] + atomicAdd(&cur[d], 1);
    col[pos] = s;
    wv[pos]  = dinv[s];
}

// Y[base+r][t] = sum_k X[base+r][k] * W[k][t]
template<int K, int R>
__global__ __launch_bounds__(128) void k_gemm(const float* __restrict__ X,
                                              const float* __restrict__ W,
                                              float* __restrict__ Y) {
    const int t = threadIdx.x;
    const long base = (long)blockIdx.x * R;
    float acc[R];
#pragma unroll
    for (int r = 0; r < R; ++r) acc[r] = 0.0f;
    for (int k = 0; k < K; ++k) {
        float wvv = W[k * HID + t];
#pragma unroll
        for (int r = 0; r < R; ++r)
            acc[r] += X[(base + r) * K + k] * wvv;
    }
#pragma unroll
    for (int r = 0; r < R; ++r)
        Y[(base + r) * HID + t] = acc[r];
}

// out[i][j] = relu( dinv[i]*(Hm[i][j]*dinv[i] + sum_k wv[k]*Hm[col[k]][j]) + b[j] )
template<bool RELU>
__global__ __launch_bounds__(128) void k_agg(const float* __restrict__ Hm,
                                             const int* __restrict__ rowptr,
                                             const int* __restrict__ col,
                                             const float* __restrict__ wv,
                                             const float* __restrict__ dinv,
                                             const float* __restrict__ bias,
                                             float* __restrict__ out) {
    const int i = blockIdx.x;
    const int j = threadIdx.x;
    const float di = dinv[i];
    int k = rowptr[i];
    const int end = rowptr[i + 1];
    float acc = Hm[(long)i * HID + j] * di;
    for (; k + 3 < end; k += 4) {
        int   s0 = col[k],  s1 = col[k+1], s2 = col[k+2], s3 = col[k+3];
        float w0 = wv[k],   w1 = wv[k+1],  w2 = wv[k+2],  w3 = wv[k+3];
        float h0 = Hm[(long)s0 * HID + j];
        float h1 = Hm[(long)s1 * HID + j];
        float h2 = Hm[(long)s2 * HID + j];
        float h3 = Hm[(long)s3 * HID + j];
        acc += w0 * h0 + w1 * h1 + w2 * h2 + w3 * h3;
    }
    for (; k < end; ++k)
        acc += wv[k] * Hm[(long)col[k] * HID + j];
    float r = di * acc + bias[j];
    out[(long)i * HID + j] = RELU ? fmaxf(r, 0.0f) : r;
}

__global__ __launch_bounds__(256) void k_head(const float* __restrict__ h,
                                              const float* __restrict__ W3,
                                              const float* __restrict__ b3,
                                              float* __restrict__ out) {
    __shared__ float w[HID * 2];
    int t = threadIdx.x;
    w[t] = W3[t];               // 256 = HID*2 exactly
    __syncthreads();
    int i = blockIdx.x * 256 + t;
    if (i >= NN) return;
    const float4* row = (const float4*)(h + (long)i * HID);
    float a0 = 0.f, a1 = 0.f;
#pragma unroll
    for (int k4 = 0; k4 < HID / 4; ++k4) {
        float4 v = row[k4];
        a0 += v.x * w[(k4 * 4 + 0) * 2 + 0] + v.y * w[(k4 * 4 + 1) * 2 + 0]
            + v.z * w[(k4 * 4 + 2) * 2 + 0] + v.w * w[(k4 * 4 + 3) * 2 + 0];
        a1 += v.x * w[(k4 * 4 + 0) * 2 + 1] + v.y * w[(k4 * 4 + 1) * 2 + 1]
            + v.z * w[(k4 * 4 + 2) * 2 + 1] + v.w * w[(k4 * 4 + 3) * 2 + 1];
    }
    out[(long)i * 2 + 0] = a0 + b3[0];
    out[(long)i * 2 + 1] = a1 + b3[1];
}

extern "C" void kernel_launch(void* const* d_in, const int* in_sizes, int n_in,
                              void* d_out, int out_size, void* d_ws, size_t ws_size,
                              hipStream_t stream) {
    const float* x   = (const float*)d_in[0];
    const int*   ei  = (const int*)d_in[1];
    const float* W1  = (const float*)d_in[2];
    const float* b1  = (const float*)d_in[3];
    const float* W2  = (const float*)d_in[4];
    const float* b2  = (const float*)d_in[5];
    const float* W3  = (const float*)d_in[6];
    const float* b3  = (const float*)d_in[7];
    float* out = (float*)d_out;

    const int* srcA = ei;           // edge_index[0]
    const int* dstA = ei + NE;      // edge_index[1]

    // workspace layout (256B-aligned slabs)
    char* p = (char*)d_ws;
    auto alloc = [&](size_t bytes) {
        char* r = p;
        p += (bytes + 255) & ~(size_t)255;
        return r;
    };
    float* dinv   = (float*)alloc(NN * 4);
    int*   counts = (int*)  alloc(NN * 4);          // later reused as cursor
    int*   rowptr = (int*)  alloc((NN + 1) * 4);
    int*   bsum   = (int*)  alloc(512 * 4);
    int*   col    = (int*)  alloc((size_t)NE * 4);
    float* wv     = (float*)alloc((size_t)NE * 4);
    float* buf1   = (float*)alloc((size_t)NN * HID * 4);
    float* buf2   = (float*)alloc((size_t)NN * HID * 4);

    const int nb_n = (NN + 255) / 256;   // 391
    const int nb_e = (NE + 255) / 256;   // 6250

    // ---- CSR build ----
    k_zero_counts<<<nb_n, 256, 0, stream>>>(counts);
    k_hist<<<nb_e, 256, 0, stream>>>(dstA, counts);
    k_dinv<<<nb_n, 256, 0, stream>>>(counts, dinv);
    k_scanA<<<nb_n, 256, 0, stream>>>(counts, rowptr, bsum);
    k_scanB<<<1, 512, 0, stream>>>(bsum, nb_n);
    k_scanC<<<nb_n, 256, 0, stream>>>(rowptr, bsum, counts);
    k_fill<<<nb_e, 256, 0, stream>>>(srcA, dstA, dinv, rowptr, counts, col, wv);

    // ---- layer 1 ----
    k_gemm<FIN, 8><<<NN / 8, 128, 0, stream>>>(x, W1, buf1);
    k_agg<true><<<NN, 128, 0, stream>>>(buf1, rowptr, col, wv, dinv, b1, buf2);

    // ---- layer 2 ----
    k_gemm<HID, 8><<<NN / 8, 128, 0, stream>>>(buf2, W2, buf1);
    k_agg<true><<<NN, 128, 0, stream>>>(buf1, rowptr, col, wv, dinv, b2, buf2);

    // ---- head ----
    k_head<<<nb_n, 256, 0, stream>>>(buf2, W3, b3, out);
}

// Round 3
// 538.837 us; speedup vs baseline: 3.2674x; 1.2886x over previous
//
#include <hip/hip_runtime.h>

// EllipticGNN: 2-layer GCN + linear head, f32. CSR-gather aggregation +
// LDS-tiled register-blocked GEMM.

constexpr int NN   = 100000;
constexpr int NE   = 1600000;
constexpr int FIN  = 165;
constexpr int HID  = 128;

__global__ __launch_bounds__(256) void k_zero_counts(int* __restrict__ c) {
    int i = blockIdx.x * 256 + threadIdx.x;
    if (i < NN) c[i] = 0;
}

__global__ __launch_bounds__(256) void k_hist(const int* __restrict__ dst,
                                              int* __restrict__ c) {
    int i = blockIdx.x * 256 + threadIdx.x;
    if (i < NE) atomicAdd(&c[dst[i]], 1);
}

__global__ __launch_bounds__(256) void k_dinv(const int* __restrict__ c,
                                              float* __restrict__ dinv) {
    int i = blockIdx.x * 256 + threadIdx.x;
    if (i < NN) dinv[i] = rsqrtf((float)c[i] + 1.0f);   // +1 self-loop
}

// block-level exclusive scan of counts -> rowptr (partial), block sums -> bsum
__global__ __launch_bounds__(256) void k_scanA(const int* __restrict__ c,
                                               int* __restrict__ rowptr,
                                               int* __restrict__ bsum) {
    __shared__ int s[256];
    int t = threadIdx.x;
    int i = blockIdx.x * 256 + t;
    int v = (i < NN) ? c[i] : 0;
    s[t] = v; __syncthreads();
    for (int off = 1; off < 256; off <<= 1) {
        int add = (t >= off) ? s[t - off] : 0;
        __syncthreads();
        s[t] += add;
        __syncthreads();
    }
    if (i < NN) rowptr[i] = s[t] - v;          // exclusive within block
    if (t == 255) bsum[blockIdx.x] = s[255];
}

// exclusive scan of block sums in place (nb <= 512)
__global__ __launch_bounds__(512) void k_scanB(int* __restrict__ bsum, int nb) {
    __shared__ int s[512];
    int t = threadIdx.x;
    int v = (t < nb) ? bsum[t] : 0;
    s[t] = v; __syncthreads();
    for (int off = 1; off < 512; off <<= 1) {
        int add = (t >= off) ? s[t - off] : 0;
        __syncthreads();
        s[t] += add;
        __syncthreads();
    }
    if (t < nb) bsum[t] = s[t] - v;
}

// add block offsets; re-zero counts (reused as fill cursor); rowptr[NN] = NE
__global__ __launch_bounds__(256) void k_scanC(int* __restrict__ rowptr,
                                               const int* __restrict__ bsum,
                                               int* __restrict__ c) {
    int i = blockIdx.x * 256 + threadIdx.x;
    if (i < NN) { rowptr[i] += bsum[blockIdx.x]; c[i] = 0; }
    if (i == 0) rowptr[NN] = NE;
}

__global__ __launch_bounds__(256) void k_fill(const int* __restrict__ src,
                                              const int* __restrict__ dst,
                                              const float* __restrict__ dinv,
                                              const int* __restrict__ rowptr,
                                              int* __restrict__ cur,
                                              int* __restrict__ col,
                                              float* __restrict__ wv) {
    int e = blockIdx.x * 256 + threadIdx.x;
    if (e >= NE) return;
    int s = src[e], d = dst[e];
    int pos = rowptr[d] + atomicAdd(&cur[d], 1);
    col[pos] = s;
    wv[pos]  = dinv[s];
}

// Tiled GEMM: Y[64 x 128 tile] = X[64 x K] @ W[K x 128].
// 256 threads: thread = (rg = t>>5 in 0..7, cg = t&31). Each thread owns an
// 8-row x 4-col register tile. X tile staged in LDS (row stride KP, 16B
// aligned); W rows read as coalesced float4 (hot in L1/L2).
template<int K, int KP, bool VEC4>
__global__ __launch_bounds__(256) void k_gemm_t(const float* __restrict__ X,
                                                const float* __restrict__ W,
                                                float* __restrict__ Y) {
    __shared__ float Xs[64 * KP];
    const int tid = threadIdx.x;
    const long base = (long)blockIdx.x * 64;
    const int rows = (NN - base < 64) ? (int)(NN - base) : 64;

    if (VEC4) {
        const float4* Xg = (const float4*)(X + base * K);
        const int tot4 = rows * (K / 4);
        for (int i = tid; i < tot4; i += 256) {
            int r = i / (K / 4), c4 = i % (K / 4);
            *(float4*)&Xs[r * KP + c4 * 4] = Xg[i];
        }
    } else {
        const int tot = rows * K;
        const float* Xg = X + base * K;
        for (int i = tid; i < tot; i += 256) {
            int r = i / K, c = i % K;
            Xs[r * KP + c] = Xg[i];
        }
    }
    __syncthreads();

    const int cg = tid & 31;
    const int rg = tid >> 5;
    const float* Wp = W + 4 * cg;
    const float* Xrow = &Xs[rg * 8 * KP];

    float acc[8][4];
#pragma unroll
    for (int r = 0; r < 8; ++r)
#pragma unroll
        for (int c = 0; c < 4; ++c) acc[r][c] = 0.0f;

    int k = 0;
    for (; k + 4 <= K; k += 4) {
        float4 w0 = *(const float4*)(Wp + (k + 0) * HID);
        float4 w1 = *(const float4*)(Wp + (k + 1) * HID);
        float4 w2 = *(const float4*)(Wp + (k + 2) * HID);
        float4 w3 = *(const float4*)(Wp + (k + 3) * HID);
#pragma unroll
        for (int r = 0; r < 8; ++r) {
            float4 xv = *(const float4*)&Xrow[r * KP + k];
            acc[r][0] += xv.x * w0.x + xv.y * w1.x + xv.z * w2.x + xv.w * w3.x;
            acc[r][1] += xv.x * w0.y + xv.y * w1.y + xv.z * w2.y + xv.w * w3.y;
            acc[r][2] += xv.x * w0.z + xv.y * w1.z + xv.z * w2.z + xv.w * w3.z;
            acc[r][3] += xv.x * w0.w + xv.y * w1.w + xv.z * w2.w + xv.w * w3.w;
        }
    }
    for (; k < K; ++k) {                       // tail (K=165)
        float4 wt = *(const float4*)(Wp + k * HID);
#pragma unroll
        for (int r = 0; r < 8; ++r) {
            float xs = Xrow[r * KP + k];
            acc[r][0] += xs * wt.x;
            acc[r][1] += xs * wt.y;
            acc[r][2] += xs * wt.z;
            acc[r][3] += xs * wt.w;
        }
    }

#pragma unroll
    for (int r = 0; r < 8; ++r) {
        long row = base + rg * 8 + r;
        if (row < NN) {
            float4 o = make_float4(acc[r][0], acc[r][1], acc[r][2], acc[r][3]);
            *(float4*)&Y[row * HID + 4 * cg] = o;
        }
    }
}

// out[i][j] = relu( dinv[i]*(Hm[i][j]*dinv[i] + sum_k wv[k]*Hm[col[k]][j]) + b[j] )
template<bool RELU>
__global__ __launch_bounds__(128) void k_agg(const float* __restrict__ Hm,
                                             const int* __restrict__ rowptr,
                                             const int* __restrict__ col,
                                             const float* __restrict__ wv,
                                             const float* __restrict__ dinv,
                                             const float* __restrict__ bias,
                                             float* __restrict__ out) {
    const int i = blockIdx.x;
    const int j = threadIdx.x;
    const float di = dinv[i];
    int k = rowptr[i];
    const int end = rowptr[i + 1];
    float acc = Hm[(long)i * HID + j] * di;
    for (; k + 3 < end; k += 4) {
        int   s0 = col[k],  s1 = col[k+1], s2 = col[k+2], s3 = col[k+3];
        float w0 = wv[k],   w1 = wv[k+1],  w2 = wv[k+2],  w3 = wv[k+3];
        float h0 = Hm[(long)s0 * HID + j];
        float h1 = Hm[(long)s1 * HID + j];
        float h2 = Hm[(long)s2 * HID + j];
        float h3 = Hm[(long)s3 * HID + j];
        acc += w0 * h0 + w1 * h1 + w2 * h2 + w3 * h3;
    }
    for (; k < end; ++k)
        acc += wv[k] * Hm[(long)col[k] * HID + j];
    float r = di * acc + bias[j];
    out[(long)i * HID + j] = RELU ? fmaxf(r, 0.0f) : r;
}

__global__ __launch_bounds__(256) void k_head(const float* __restrict__ h,
                                              const float* __restrict__ W3,
                                              const float* __restrict__ b3,
                                              float* __restrict__ out) {
    __shared__ float w[HID * 2];
    int t = threadIdx.x;
    w[t] = W3[t];               // 256 = HID*2 exactly
    __syncthreads();
    int i = blockIdx.x * 256 + t;
    if (i >= NN) return;
    const float4* row = (const float4*)(h + (long)i * HID);
    float a0 = 0.f, a1 = 0.f;
#pragma unroll
    for (int k4 = 0; k4 < HID / 4; ++k4) {
        float4 v = row[k4];
        a0 += v.x * w[(k4 * 4 + 0) * 2 + 0] + v.y * w[(k4 * 4 + 1) * 2 + 0]
            + v.z * w[(k4 * 4 + 2) * 2 + 0] + v.w * w[(k4 * 4 + 3) * 2 + 0];
        a1 += v.x * w[(k4 * 4 + 0) * 2 + 1] + v.y * w[(k4 * 4 + 1) * 2 + 1]
            + v.z * w[(k4 * 4 + 2) * 2 + 1] + v.w * w[(k4 * 4 + 3) * 2 + 1];
    }
    out[(long)i * 2 + 0] = a0 + b3[0];
    out[(long)i * 2 + 1] = a1 + b3[1];
}

extern "C" void kernel_launch(void* const* d_in, const int* in_sizes, int n_in,
                              void* d_out, int out_size, void* d_ws, size_t ws_size,
                              hipStream_t stream) {
    const float* x   = (const float*)d_in[0];
    const int*   ei  = (const int*)d_in[1];
    const float* W1  = (const float*)d_in[2];
    const float* b1  = (const float*)d_in[3];
    const float* W2  = (const float*)d_in[4];
    const float* b2  = (const float*)d_in[5];
    const float* W3  = (const float*)d_in[6];
    const float* b3  = (const float*)d_in[7];
    float* out = (float*)d_out;

    const int* srcA = ei;           // edge_index[0]
    const int* dstA = ei + NE;      // edge_index[1]

    // workspace layout (256B-aligned slabs)
    char* p = (char*)d_ws;
    auto alloc = [&](size_t bytes) {
        char* r = p;
        p += (bytes + 255) & ~(size_t)255;
        return r;
    };
    float* dinv   = (float*)alloc(NN * 4);
    int*   counts = (int*)  alloc(NN * 4);          // later reused as cursor
    int*   rowptr = (int*)  alloc((NN + 1) * 4);
    int*   bsum   = (int*)  alloc(512 * 4);
    int*   col    = (int*)  alloc((size_t)NE * 4);
    float* wv     = (float*)alloc((size_t)NE * 4);
    float* buf1   = (float*)alloc((size_t)NN * HID * 4);
    float* buf2   = (float*)alloc((size_t)NN * HID * 4);

    const int nb_n = (NN + 255) / 256;   // 391
    const int nb_e = (NE + 255) / 256;   // 6250
    const int nb_g = (NN + 63) / 64;     // 1563

    // ---- CSR build ----
    k_zero_counts<<<nb_n, 256, 0, stream>>>(counts);
    k_hist<<<nb_e, 256, 0, stream>>>(dstA, counts);
    k_dinv<<<nb_n, 256, 0, stream>>>(counts, dinv);
    k_scanA<<<nb_n, 256, 0, stream>>>(counts, rowptr, bsum);
    k_scanB<<<1, 512, 0, stream>>>(bsum, nb_n);
    k_scanC<<<nb_n, 256, 0, stream>>>(rowptr, bsum, counts);
    k_fill<<<nb_e, 256, 0, stream>>>(srcA, dstA, dinv, rowptr, counts, col, wv);

    // ---- layer 1 ----  (K=165, LDS row stride 168 keeps 16B alignment)
    k_gemm_t<FIN, 168, false><<<nb_g, 256, 0, stream>>>(x, W1, buf1);
    k_agg<true><<<NN, 128, 0, stream>>>(buf1, rowptr, col, wv, dinv, b1, buf2);

    // ---- layer 2 ----  (K=128, stride 132 = 16B-aligned, float4 staging)
    k_gemm_t<HID, 132, true><<<nb_g, 256, 0, stream>>>(buf2, W2, buf1);
    k_agg<true><<<NN, 128, 0, stream>>>(buf1, rowptr, col, wv, dinv, b2, buf2);

    // ---- head ----
    k_head<<<nb_n, 256, 0, stream>>>(buf2, W3, b3, out);
}